// Round 1
// baseline (543.626 us; speedup 1.0000x reference)
//
#include <hip/hip_runtime.h>
#include <math.h>

#define TT 256
#define HH 128
#define DH 64

__device__ __forceinline__ void enc6(float t, float e[6]) {
  float x = 6.2831853071795864769f * t;
  float a0 = x / 86400.0f, a1 = x / 604800.0f, a2 = x / 2592000.0f;
  e[0] = sinf(a0); e[1] = sinf(a1); e[2] = sinf(a2);
  e[3] = cosf(a0); e[4] = cosf(a1); e[5] = cosf(a2);
}

// seqs[b,t,:] = keep * (item_emb[log_seqs]*sqrt(H) + enc6 @ time_proj.T); also store sc6
__global__ __launch_bounds__(128) void embed_kernel(
    const int* __restrict__ log_seqs, const float* __restrict__ time_seq,
    const float* __restrict__ item_emb, const float* __restrict__ time_proj,
    float* __restrict__ seqs, float* __restrict__ sc6) {
  int row = blockIdx.x;
  int h = threadIdx.x;
  float t = time_seq[row];
  float e[6]; enc6(t, e);
  int idx = log_seqs[row];
  const float* tp = time_proj + h * 6;
  float val = item_emb[(size_t)idx * HH + h] * 11.313708498984761f; // sqrt(128)
  val += e[0]*tp[0] + e[1]*tp[1] + e[2]*tp[2] + e[3]*tp[3] + e[4]*tp[4] + e[5]*tp[5];
  seqs[(size_t)row * HH + h] = (idx != 0) ? val : 0.0f;
  if (h < 6) sc6[row * 6 + h] = e[h];
}

__global__ __launch_bounds__(128) void ln_kernel(
    const float* __restrict__ in, const float* __restrict__ g,
    const float* __restrict__ b, float* __restrict__ out) {
  int row = blockIdx.x, tid = threadIdx.x;
  __shared__ float red[4];
  float x = in[(size_t)row * HH + tid];
  float s = x;
  #pragma unroll
  for (int o = 32; o > 0; o >>= 1) s += __shfl_xor(s, o);
  int wv = tid >> 6;
  if ((tid & 63) == 0) red[wv] = s;
  __syncthreads();
  float mu = (red[0] + red[1]) * (1.0f / HH);
  float dv = x - mu;
  float v2 = dv * dv;
  #pragma unroll
  for (int o = 32; o > 0; o >>= 1) v2 += __shfl_xor(v2, o);
  if ((tid & 63) == 0) red[2 + wv] = v2;
  __syncthreads();
  float var = (red[2] + red[3]) * (1.0f / HH);
  out[(size_t)row * HH + tid] = dv * rsqrtf(var + 1e-8f) * g[tid] + b[tid];
}

// out[m,n] = act( sum_d A[m,d]*W[n*ldw+d] + bias + addPos[m%T] + res[m] ), optional keep-mask
__global__ __launch_bounds__(128) void gemm128(
    const float* __restrict__ A, const float* __restrict__ W, int ldw,
    const float* __restrict__ bias, int bias_per_b,
    const float* __restrict__ res, const float* __restrict__ addPos,
    const int* __restrict__ keep_ls, int act, float* __restrict__ out) {
  __shared__ float At[16][HH];
  int n = threadIdx.x;
  int m0 = blockIdx.x * 16;
  #pragma unroll
  for (int r = 0; r < 16; ++r) At[r][n] = A[(size_t)(m0 + r) * HH + n];
  __syncthreads();
  float acc[16];
  #pragma unroll
  for (int r = 0; r < 16; ++r) acc[r] = 0.f;
  const float* wr = W + (size_t)n * ldw;
  for (int d = 0; d < HH; d += 4) {
    float4 w = *(const float4*)(wr + d);
    #pragma unroll
    for (int r = 0; r < 16; ++r) {
      float4 a = *(const float4*)(&At[r][d]);
      acc[r] += a.x * w.x + a.y * w.y + a.z * w.z + a.w * w.w;
    }
  }
  #pragma unroll
  for (int r = 0; r < 16; ++r) {
    int m = m0 + r;
    float v = acc[r];
    if (bias) v += bias_per_b ? bias[(m >> 8) * HH + n] : bias[n];
    if (addPos) v += addPos[(size_t)(m & 255) * HH + n];
    if (res) v += res[(size_t)m * HH + n];
    if (act == 1) v = fmaxf(v, 0.f);
    else if (act == 2) v = 0.5f * v * (1.0f + erff(v * 0.70710678118654752f));
    if (keep_ls && keep_ls[m] == 0) v = 0.f;
    out[(size_t)m * HH + n] = v;
  }
}

// One block per (b,h,q) row. K already contains absK, V contains absV.
__global__ __launch_bounds__(256) void attn_kernel(
    const float* __restrict__ Qb, const float* __restrict__ Kb,
    const float* __restrict__ Vb, const float* __restrict__ Qn,
    const int* __restrict__ log_seqs, const int* __restrict__ tmat,
    const float* __restrict__ sc6,
    const float* __restrict__ tKe, const float* __restrict__ tVe,
    const float* __restrict__ lambdas, float* __restrict__ out) {
  int blk = blockIdx.x;
  int q = blk & 255;
  int h = (blk >> 8) & 1;
  int b = blk >> 9;
  int tid = threadIdx.x;
  int wv = tid >> 6;
  __shared__ float qrow[DH];
  __shared__ float scq[6];
  __shared__ float Abuf[TT];
  __shared__ int tmbuf[TT];
  __shared__ float red[8];
  __shared__ float part[4][DH];
  int hoff = h * DH;
  size_t qbase = ((size_t)(b * TT + q)) * HH + hoff;
  if (tid < DH) qrow[tid] = Qb[qbase + tid];
  if (tid < 6) scq[tid] = sc6[(b * TT + q) * 6 + tid];
  __syncthreads();
  int k = tid;
  int tm = tmat[((size_t)(b * TT + q)) * TT + k];
  tmbuf[k] = tm;
  const float* kp = Kb + ((size_t)(b * TT + k)) * HH + hoff;
  const float* tp = tKe + (size_t)tm * HH + hoff;
  float acc = 0.f;
  #pragma unroll
  for (int d = 0; d < DH; d += 4) {
    float4 kv = *(const float4*)(kp + d);
    float4 tv = *(const float4*)(tp + d);
    acc += qrow[d+0]*(kv.x+tv.x) + qrow[d+1]*(kv.y+tv.y)
         + qrow[d+2]*(kv.z+tv.z) + qrow[d+3]*(kv.w+tv.w);
  }
  float l0 = lambdas[0], l1 = lambdas[1], l2 = lambdas[2];
  const float* sck = sc6 + (b * TT + k) * 6;
  float pb = l0*(scq[0]*sck[0] + scq[3]*sck[3])
           + l1*(scq[1]*sck[1] + scq[4]*sck[4])
           + l2*(scq[2]*sck[2] + scq[5]*sck[5]);
  float s = acc * 0.125f + pb;  // /sqrt(64)
  if (k > q || log_seqs[b * TT + k] == 0) s = -1e9f;
  // block softmax over 256
  float mx = s;
  #pragma unroll
  for (int o = 32; o > 0; o >>= 1) mx = fmaxf(mx, __shfl_xor(mx, o));
  if ((tid & 63) == 0) red[wv] = mx;
  __syncthreads();
  float gmx = fmaxf(fmaxf(red[0], red[1]), fmaxf(red[2], red[3]));
  float ev = __expf(s - gmx);
  Abuf[k] = ev;
  float sm = ev;
  #pragma unroll
  for (int o = 32; o > 0; o >>= 1) sm += __shfl_xor(sm, o);
  if ((tid & 63) == 0) red[4 + wv] = sm;
  __syncthreads();
  float inv = 1.0f / (red[4] + red[5] + red[6] + red[7]);
  // PV phase: wave wv handles k in [64*wv, 64*wv+64), lane = d
  int d = tid & 63;
  float pacc = 0.f;
  int kb0 = wv * 64;
  for (int kk = 0; kk < 64; ++kk) {
    int kt = kb0 + kk;
    float a = Abuf[kt];
    int tm2 = tmbuf[kt];
    pacc += a * (Vb[((size_t)(b * TT + kt)) * HH + hoff + d]
               + tVe[(size_t)tm2 * HH + hoff + d]);
  }
  part[wv][d] = pacc;
  __syncthreads();
  if (tid < 64) {
    float o = (part[0][d] + part[1][d] + part[2][d] + part[3][d]) * inv;
    out[qbase + d] = Qn[qbase + d] + o;
  }
}

// hp1[b,n] = fus_b1[n] + sum_d Hper[b,d] * fus_W1[n, 128+d],  Hper = (enc6@time_proj.T)@pred_W.T
__global__ __launch_bounds__(128) void hper_kernel(
    const float* __restrict__ target_t, const float* __restrict__ time_proj,
    const float* __restrict__ pred_W, const float* __restrict__ fus_W1,
    const float* __restrict__ fus_b1, float* __restrict__ hp1) {
  int b = blockIdx.x, h = threadIdx.x;
  __shared__ float te[HH], hp[HH];
  float e[6]; enc6(target_t[b], e);
  const float* tp = time_proj + h * 6;
  te[h] = e[0]*tp[0]+e[1]*tp[1]+e[2]*tp[2]+e[3]*tp[3]+e[4]*tp[4]+e[5]*tp[5];
  __syncthreads();
  float u = 0.f;
  const float* pw = pred_W + (size_t)h * HH;
  for (int d = 0; d < HH; ++d) u += te[d] * pw[d];
  hp[h] = u;
  __syncthreads();
  float w = fus_b1[h];
  const float* f1 = fus_W1 + (size_t)h * 256 + 128;
  for (int d = 0; d < HH; ++d) w += hp[d] * f1[d];
  hp1[b * HH + h] = w;
}

__global__ __launch_bounds__(128) void logits_kernel(
    const float* __restrict__ fused, const float* __restrict__ item_emb,
    const int* __restrict__ pos, const int* __restrict__ neg,
    float* __restrict__ out) {
  int row = blockIdx.x, tid = threadIdx.x;
  __shared__ float red[4];
  float f = fused[(size_t)row * HH + tid];
  int pi = pos[row], ni = neg[row];
  float p = f * item_emb[(size_t)pi * HH + tid];
  float qv = f * item_emb[(size_t)ni * HH + tid];
  #pragma unroll
  for (int o = 32; o > 0; o >>= 1) { p += __shfl_xor(p, o); qv += __shfl_xor(qv, o); }
  int wv = tid >> 6;
  if ((tid & 63) == 0) { red[wv] = p; red[2 + wv] = qv; }
  __syncthreads();
  if (tid == 0) {
    out[row] = red[0] + red[1];
    out[2048 + row] = red[2] + red[3];
  }
}

extern "C" void kernel_launch(void* const* d_in, const int* in_sizes, int n_in,
                              void* d_out, int out_size, void* d_ws, size_t ws_size,
                              hipStream_t stream) {
  const int*   log_seqs   = (const int*)d_in[0];
  const int*   tmat       = (const int*)d_in[1];
  const float* time_seq   = (const float*)d_in[2];
  const int*   pos_seqs   = (const int*)d_in[3];
  const int*   neg_seqs   = (const int*)d_in[4];
  const float* target_t   = (const float*)d_in[5];
  const float* item_emb   = (const float*)d_in[6];
  const float* abs_pos_K  = (const float*)d_in[7];
  const float* abs_pos_V  = (const float*)d_in[8];
  const float* time_K_emb = (const float*)d_in[9];
  const float* time_V_emb = (const float*)d_in[10];
  const float* Wq = (const float*)d_in[11];
  const float* bq = (const float*)d_in[12];
  const float* Wk = (const float*)d_in[13];
  const float* bk = (const float*)d_in[14];
  const float* Wv = (const float*)d_in[15];
  const float* bv = (const float*)d_in[16];
  const float* attn_ln_g = (const float*)d_in[17];
  const float* attn_ln_b = (const float*)d_in[18];
  const float* fwd_ln_g = (const float*)d_in[19];
  const float* fwd_ln_b = (const float*)d_in[20];
  const float* w1 = (const float*)d_in[21];
  const float* b1 = (const float*)d_in[22];
  const float* w2 = (const float*)d_in[23];
  const float* b2 = (const float*)d_in[24];
  const float* last_ln_g = (const float*)d_in[25];
  const float* last_ln_b = (const float*)d_in[26];
  const float* time_proj = (const float*)d_in[27];
  const float* lambdas = (const float*)d_in[28];
  const float* pred_W = (const float*)d_in[29];
  const float* fus_W1 = (const float*)d_in[30];
  const float* fus_b1 = (const float*)d_in[31];
  const float* fus_W2 = (const float*)d_in[32];
  const float* fus_b2 = (const float*)d_in[33];
  (void)in_sizes; (void)n_in; (void)out_size; (void)ws_size;

  float* out = (float*)d_out;
  float* ws = (float*)d_ws;
  const int M = 8 * TT;  // 2048
  float* SC6  = ws;                 // M*6
  float* SEQS = SC6 + M * 6;
  float* QN   = SEQS + M * HH;
  float* QB   = QN + M * HH;
  float* KB   = QB + M * HH;
  float* VB   = KB + M * HH;
  float* XB   = VB + M * HH;
  float* HB   = XB + M * HH;
  float* HP1  = HB + M * HH;        // 8*128

  embed_kernel<<<M, HH, 0, stream>>>(log_seqs, time_seq, item_emb, time_proj, SEQS, SC6);
  for (int l = 0; l < 2; ++l) {
    const size_t wo = (size_t)l * HH * HH;
    const size_t bo = (size_t)l * HH;
    ln_kernel<<<M, HH, 0, stream>>>(SEQS, attn_ln_g + bo, attn_ln_b + bo, QN);
    gemm128<<<M / 16, HH, 0, stream>>>(QN, Wq + wo, 128, bq + bo, 0, nullptr, nullptr, nullptr, 0, QB);
    gemm128<<<M / 16, HH, 0, stream>>>(SEQS, Wk + wo, 128, bk + bo, 0, nullptr, abs_pos_K, nullptr, 0, KB);
    gemm128<<<M / 16, HH, 0, stream>>>(SEQS, Wv + wo, 128, bv + bo, 0, nullptr, abs_pos_V, nullptr, 0, VB);
    attn_kernel<<<8 * 2 * TT, 256, 0, stream>>>(QB, KB, VB, QN, log_seqs, tmat, SC6,
                                                time_K_emb, time_V_emb, lambdas, SEQS);
    ln_kernel<<<M, HH, 0, stream>>>(SEQS, fwd_ln_g + bo, fwd_ln_b + bo, XB);
    gemm128<<<M / 16, HH, 0, stream>>>(XB, w1 + wo, 128, b1 + bo, 0, nullptr, nullptr, nullptr, 1, HB);
    gemm128<<<M / 16, HH, 0, stream>>>(HB, w2 + wo, 128, b2 + bo, 0, XB, nullptr, log_seqs, 0, SEQS);
  }
  ln_kernel<<<M, HH, 0, stream>>>(SEQS, last_ln_g, last_ln_b, QN);
  hper_kernel<<<8, HH, 0, stream>>>(target_t, time_proj, pred_W, fus_W1, fus_b1, HP1);
  gemm128<<<M / 16, HH, 0, stream>>>(QN, fus_W1, 256, HP1, 1, nullptr, nullptr, nullptr, 2, HB);
  gemm128<<<M / 16, HH, 0, stream>>>(HB, fus_W2, 128, fus_b2, 0, nullptr, nullptr, nullptr, 0, XB);
  logits_kernel<<<M, HH, 0, stream>>>(XB, item_emb, pos_seqs, neg_seqs, out);
}

// Round 3
// 334.192 us; speedup vs baseline: 1.6267x; 1.6267x over previous
//
#include <hip/hip_runtime.h>
#include <math.h>

#define TT 256
#define HH 128
#define QT 4

__device__ __forceinline__ void enc6(float t, float e[6]) {
  float x = 6.2831853071795864769f * t;
  float a0 = x / 86400.0f, a1 = x / 604800.0f, a2 = x / 2592000.0f;
  e[0] = sinf(a0); e[1] = sinf(a1); e[2] = sinf(a2);
  e[3] = cosf(a0); e[4] = cosf(a1); e[5] = cosf(a2);
}

__device__ __forceinline__ unsigned short f2bf(float x) {
  unsigned int u = __float_as_uint(x);
  u = (u + 0x7FFFu + ((u >> 16) & 1u)) >> 16;
  return (unsigned short)u;
}

__global__ __launch_bounds__(128) void embed_kernel(
    const int* __restrict__ log_seqs, const float* __restrict__ time_seq,
    const float* __restrict__ item_emb, const float* __restrict__ time_proj,
    float* __restrict__ seqs, float* __restrict__ sc6) {
  int row = blockIdx.x;
  int h = threadIdx.x;
  float t = time_seq[row];
  float e[6]; enc6(t, e);
  int idx = log_seqs[row];
  const float* tp = time_proj + h * 6;
  float val = item_emb[(size_t)idx * HH + h] * 11.313708498984761f; // sqrt(128)
  val += e[0]*tp[0] + e[1]*tp[1] + e[2]*tp[2] + e[3]*tp[3] + e[4]*tp[4] + e[5]*tp[5];
  seqs[(size_t)row * HH + h] = (idx != 0) ? val : 0.0f;
  if (h < 6) sc6[row * 6 + h] = e[h];
}

// which = blockIdx.x>>8: 0=Q (with LN, writes QN too), 1=K(+absK), 2=V(+absV). 8-row tiles.
__global__ __launch_bounds__(128) void qkv_fused(
    const float* __restrict__ S,
    const float* __restrict__ Wq, const float* __restrict__ bq,
    const float* __restrict__ Wk, const float* __restrict__ bk,
    const float* __restrict__ Wv, const float* __restrict__ bv,
    const float* __restrict__ lng, const float* __restrict__ lnb,
    const float* __restrict__ absK, const float* __restrict__ absV,
    float* __restrict__ QN, float* __restrict__ QB,
    float* __restrict__ KB, float* __restrict__ VB) {
  int which = blockIdx.x >> 8;
  int m0 = (blockIdx.x & 255) * 8;
  int n = threadIdx.x;
  __shared__ float At[8][132];
  __shared__ float mu[8], rs[8];
  #pragma unroll
  for (int r = 0; r < 8; ++r) At[r][n] = S[(size_t)(m0 + r) * HH + n];
  __syncthreads();
  if (which == 0) {
    if (n < 64) {
      int r = n >> 3, sg = n & 7;
      float s = 0.f;
      #pragma unroll
      for (int i = 0; i < 16; ++i) s += At[r][sg * 16 + i];
      s += __shfl_xor(s, 1); s += __shfl_xor(s, 2); s += __shfl_xor(s, 4);
      if (sg == 0) mu[r] = s * (1.0f / HH);
    }
    __syncthreads();
    if (n < 64) {
      int r = n >> 3, sg = n & 7;
      float mm = mu[r], s = 0.f;
      #pragma unroll
      for (int i = 0; i < 16; ++i) { float d = At[r][sg*16+i] - mm; s += d * d; }
      s += __shfl_xor(s, 1); s += __shfl_xor(s, 2); s += __shfl_xor(s, 4);
      if (sg == 0) rs[r] = rsqrtf(s * (1.0f / HH) + 1e-8f);
    }
    __syncthreads();
    float gg = lng[n], bb = lnb[n];
    #pragma unroll
    for (int r = 0; r < 8; ++r) {
      float v = (At[r][n] - mu[r]) * rs[r] * gg + bb;
      At[r][n] = v;
      QN[(size_t)(m0 + r) * HH + n] = v;
    }
    __syncthreads();
  }
  const float* W    = which == 0 ? Wq : which == 1 ? Wk : Wv;
  const float* bias = which == 0 ? bq : which == 1 ? bk : bv;
  const float* addP = which == 1 ? absK : which == 2 ? absV : nullptr;
  float* dst        = which == 0 ? QB : which == 1 ? KB : VB;
  float acc[8];
  #pragma unroll
  for (int r = 0; r < 8; ++r) acc[r] = 0.f;
  const float* wr = W + (size_t)n * HH;
  for (int d = 0; d < HH; d += 4) {
    float4 w = *(const float4*)(wr + d);
    #pragma unroll
    for (int r = 0; r < 8; ++r) {
      float4 a = *(const float4*)(&At[r][d]);
      acc[r] = fmaf(a.x, w.x, fmaf(a.y, w.y, fmaf(a.z, w.z, fmaf(a.w, w.w, acc[r]))));
    }
  }
  float bn = bias[n];
  #pragma unroll
  for (int r = 0; r < 8; ++r) {
    int m = m0 + r;
    float v = acc[r] + bn;
    if (addP) v += addP[(size_t)(m & 255) * HH + n];
    dst[(size_t)m * HH + n] = v;
  }
}

// grid: b(8) x h(2) x qt(64); 256 thr = 4 q-waves. Tables staged in LDS as bf16.
__global__ __launch_bounds__(256) void attn_fused(
    const float* __restrict__ QB, const float* __restrict__ KB,
    const float* __restrict__ VB, const float* __restrict__ QN,
    const int* __restrict__ log_seqs, const int* __restrict__ tmat,
    const float* __restrict__ sc6, const float* __restrict__ tKe,
    const float* __restrict__ tVe, const float* __restrict__ lambdas,
    float* __restrict__ out) {
  int blk = blockIdx.x;
  int qt = blk & 63;
  int h = (blk >> 6) & 1;
  int b = blk >> 7;
  int q0 = qt << 2;
  int hoff = h << 6;
  int tid = threadIdx.x;

  __shared__ unsigned short tKs[257][64];   // bf16
  __shared__ unsigned short tVs[257][64];   // bf16
  __shared__ float Qt[QT][64];
  __shared__ float Pp[QT][256];
  __shared__ unsigned short tmq[QT][256];
  __shared__ float sk6[256 * 6];
  __shared__ float sq6[QT * 6];
  __shared__ unsigned char kmask[256];

  for (int idx = tid; idx < 257 * 16; idx += 256) {
    int row = idx >> 4, c4 = (idx & 15) << 2;
    float4 vk = *(const float4*)(tKe + (size_t)row * HH + hoff + c4);
    float4 vv = *(const float4*)(tVe + (size_t)row * HH + hoff + c4);
    uint2 a, c;
    a.x = (unsigned)f2bf(vk.x) | ((unsigned)f2bf(vk.y) << 16);
    a.y = (unsigned)f2bf(vk.z) | ((unsigned)f2bf(vk.w) << 16);
    c.x = (unsigned)f2bf(vv.x) | ((unsigned)f2bf(vv.y) << 16);
    c.y = (unsigned)f2bf(vv.z) | ((unsigned)f2bf(vv.w) << 16);
    *(uint2*)(&tKs[row][c4]) = a;
    *(uint2*)(&tVs[row][c4]) = c;
  }
  for (int idx = tid; idx < 256 * 6; idx += 256)
    sk6[idx] = sc6[(size_t)b * (256 * 6) + idx];
  { int q = tid >> 6, d = tid & 63;
    Qt[q][d] = QB[((size_t)(b * TT + q0 + q)) * HH + hoff + d]; }
  if (tid < QT * 6) sq6[tid] = sc6[((size_t)(b * TT + q0)) * 6 + tid];
  for (int idx = tid; idx < QT * 256; idx += 256) {
    int q = idx >> 8, k = idx & 255;
    tmq[q][k] = (unsigned short)tmat[((size_t)(b * TT + q0 + q)) * TT + k];
  }
  kmask[tid] = (log_seqs[b * TT + tid] == 0) ? 1 : 0;
  __syncthreads();

  int q = tid >> 6;
  int lane = tid & 63;
  int qg = q0 + q;
  float4 qreg[16];
  #pragma unroll
  for (int i = 0; i < 16; ++i) qreg[i] = *(const float4*)(&Qt[q][i << 2]);
  float l0 = lambdas[0], l1 = lambdas[1], l2 = lambdas[2];
  float sA = sq6[q*6+0], sB = sq6[q*6+1], sC = sq6[q*6+2];
  float cA = sq6[q*6+3], cB = sq6[q*6+4], cC = sq6[q*6+5];
  float sarr[4];
  #pragma unroll
  for (int j = 0; j < 4; ++j) {
    int k = lane + (j << 6);
    float sv = -1e9f;
    if (k <= qg && kmask[k] == 0) {
      int tm = tmq[q][k];
      const float* kp = KB + ((size_t)(b * TT + k)) * HH + hoff;
      float acc = 0.f;
      #pragma unroll
      for (int d4 = 0; d4 < 16; ++d4) {
        float4 kv = *(const float4*)(kp + (d4 << 2));
        uint2 tu = *(const uint2*)(&tKs[tm][d4 << 2]);
        float t0 = __uint_as_float(tu.x << 16);
        float t1 = __uint_as_float(tu.x & 0xFFFF0000u);
        float t2 = __uint_as_float(tu.y << 16);
        float t3 = __uint_as_float(tu.y & 0xFFFF0000u);
        float4 qv = qreg[d4];
        acc = fmaf(qv.x, kv.x + t0, acc);
        acc = fmaf(qv.y, kv.y + t1, acc);
        acc = fmaf(qv.z, kv.z + t2, acc);
        acc = fmaf(qv.w, kv.w + t3, acc);
      }
      const float* s6 = &sk6[k * 6];
      float pb = l0 * (sA * s6[0] + cA * s6[3])
               + l1 * (sB * s6[1] + cB * s6[4])
               + l2 * (sC * s6[2] + cC * s6[5]);
      sv = acc * 0.125f + pb;
    }
    sarr[j] = sv;
  }
  float m = fmaxf(fmaxf(sarr[0], sarr[1]), fmaxf(sarr[2], sarr[3]));
  #pragma unroll
  for (int o = 32; o > 0; o >>= 1) m = fmaxf(m, __shfl_xor(m, o));
  float p0 = __expf(sarr[0] - m), p1 = __expf(sarr[1] - m),
        p2 = __expf(sarr[2] - m), p3 = __expf(sarr[3] - m);
  float l = p0 + p1 + p2 + p3;
  #pragma unroll
  for (int o = 32; o > 0; o >>= 1) l += __shfl_xor(l, o);
  float inv = 1.0f / l;
  Pp[q][lane]       = p0 * inv;
  Pp[q][lane + 64]  = p1 * inv;
  Pp[q][lane + 128] = p2 * inv;
  Pp[q][lane + 192] = p3 * inv;
  __syncthreads();

  // masked keys have p==0 exactly (exp underflow) unless the whole row is
  // masked (m==-1e9): then process all 256 keys uniformly, matching ref.
  int kend = (m < -5e8f) ? 256 : (qg + 1);
  float oacc = 0.f;
  const float* vb = VB + ((size_t)(b * TT)) * HH + hoff + lane;
  #pragma unroll 4
  for (int k = 0; k < kend; ++k) {
    float pk = Pp[q][k];
    int tm = tmq[q][k];
    float v = vb[(size_t)k * HH];
    float tv = __uint_as_float(((unsigned)tVs[tm][lane]) << 16);
    oacc = fmaf(pk, v + tv, oacc);
  }
  size_t obase = ((size_t)(b * TT + qg)) * HH + hoff + lane;
  out[obase] = QN[obase] + oacc;
}

// LN + relu(x@W1^T+b1)@W2^T + b2 + x, keep-mask. 4-row tiles.
__global__ __launch_bounds__(128) void ffn_fused(
    const float* __restrict__ S, const float* __restrict__ W1, const float* __restrict__ b1,
    const float* __restrict__ W2, const float* __restrict__ b2,
    const float* __restrict__ lng, const float* __restrict__ lnb,
    const int* __restrict__ log_seqs, float* __restrict__ outS) {
  int m0 = blockIdx.x * 4;
  int n = threadIdx.x;
  __shared__ float Xt[4][132];
  __shared__ float Ht[4][132];
  __shared__ float mu[4], rs[4];
  #pragma unroll
  for (int r = 0; r < 4; ++r) Xt[r][n] = S[(size_t)(m0 + r) * HH + n];
  __syncthreads();
  if (n < 32) {
    int r = n >> 3, sg = n & 7;
    float s = 0.f;
    #pragma unroll
    for (int i = 0; i < 16; ++i) s += Xt[r][sg * 16 + i];
    s += __shfl_xor(s, 1); s += __shfl_xor(s, 2); s += __shfl_xor(s, 4);
    if (sg == 0) mu[r] = s * (1.0f / HH);
  }
  __syncthreads();
  if (n < 32) {
    int r = n >> 3, sg = n & 7;
    float mm = mu[r], s = 0.f;
    #pragma unroll
    for (int i = 0; i < 16; ++i) { float d = Xt[r][sg*16+i] - mm; s += d * d; }
    s += __shfl_xor(s, 1); s += __shfl_xor(s, 2); s += __shfl_xor(s, 4);
    if (sg == 0) rs[r] = rsqrtf(s * (1.0f / HH) + 1e-8f);
  }
  __syncthreads();
  float gg = lng[n], bb = lnb[n];
  #pragma unroll
  for (int r = 0; r < 4; ++r) Xt[r][n] = (Xt[r][n] - mu[r]) * rs[r] * gg + bb;
  __syncthreads();
  float acc[4] = {0.f, 0.f, 0.f, 0.f};
  const float* wr = W1 + (size_t)n * HH;
  for (int d = 0; d < HH; d += 4) {
    float4 w = *(const float4*)(wr + d);
    #pragma unroll
    for (int r = 0; r < 4; ++r) {
      float4 a = *(const float4*)(&Xt[r][d]);
      acc[r] = fmaf(a.x, w.x, fmaf(a.y, w.y, fmaf(a.z, w.z, fmaf(a.w, w.w, acc[r]))));
    }
  }
  float b1n = b1[n];
  #pragma unroll
  for (int r = 0; r < 4; ++r) Ht[r][n] = fmaxf(acc[r] + b1n, 0.f);
  __syncthreads();
  float acc2[4] = {0.f, 0.f, 0.f, 0.f};
  wr = W2 + (size_t)n * HH;
  for (int d = 0; d < HH; d += 4) {
    float4 w = *(const float4*)(wr + d);
    #pragma unroll
    for (int r = 0; r < 4; ++r) {
      float4 a = *(const float4*)(&Ht[r][d]);
      acc2[r] = fmaf(a.x, w.x, fmaf(a.y, w.y, fmaf(a.z, w.z, fmaf(a.w, w.w, acc2[r]))));
    }
  }
  float b2n = b2[n];
  #pragma unroll
  for (int r = 0; r < 4; ++r) {
    int mrow = m0 + r;
    float v = acc2[r] + b2n + Xt[r][n];
    if (log_seqs[mrow] == 0) v = 0.f;
    outS[(size_t)mrow * HH + n] = v;
  }
}

__global__ __launch_bounds__(128) void hper_kernel(
    const float* __restrict__ target_t, const float* __restrict__ time_proj,
    const float* __restrict__ pred_W, const float* __restrict__ fus_W1,
    const float* __restrict__ fus_b1, float* __restrict__ hp1) {
  int b = blockIdx.x, hth = threadIdx.x;
  __shared__ float te[HH], hp[HH];
  float e[6]; enc6(target_t[b], e);
  const float* tp = time_proj + hth * 6;
  te[hth] = e[0]*tp[0]+e[1]*tp[1]+e[2]*tp[2]+e[3]*tp[3]+e[4]*tp[4]+e[5]*tp[5];
  __syncthreads();
  float u = 0.f;
  const float* pw = pred_W + (size_t)hth * HH;
  for (int d = 0; d < HH; ++d) u += te[d] * pw[d];
  hp[hth] = u;
  __syncthreads();
  float w = fus_b1[hth];
  const float* f1 = fus_W1 + (size_t)hth * 256 + 128;
  for (int d = 0; d < HH; ++d) w += hp[d] * f1[d];
  hp1[b * HH + hth] = w;
}

// last LN + gelu(L@fus_W1[:, :128]^T + hp1) @ fus_W2^T + fus_b2 -> logits. 4-row tiles.
__global__ __launch_bounds__(128) void final_fused(
    const float* __restrict__ S, const float* __restrict__ lng, const float* __restrict__ lnb,
    const float* __restrict__ fus_W1, const float* __restrict__ HP1,
    const float* __restrict__ fus_W2, const float* __restrict__ fus_b2,
    const float* __restrict__ item_emb, const int* __restrict__ pos,
    const int* __restrict__ neg, float* __restrict__ out) {
  int m0 = blockIdx.x * 4;
  int bidx = m0 >> 8;
  int n = threadIdx.x;
  __shared__ float Xt[4][132];
  __shared__ float Ht[4][132];
  __shared__ float Ft[4][132];
  __shared__ float mu[4], rs[4];
  #pragma unroll
  for (int r = 0; r < 4; ++r) Xt[r][n] = S[(size_t)(m0 + r) * HH + n];
  __syncthreads();
  if (n < 32) {
    int r = n >> 3, sg = n & 7;
    float s = 0.f;
    #pragma unroll
    for (int i = 0; i < 16; ++i) s += Xt[r][sg * 16 + i];
    s += __shfl_xor(s, 1); s += __shfl_xor(s, 2); s += __shfl_xor(s, 4);
    if (sg == 0) mu[r] = s * (1.0f / HH);
  }
  __syncthreads();
  if (n < 32) {
    int r = n >> 3, sg = n & 7;
    float mm = mu[r], s = 0.f;
    #pragma unroll
    for (int i = 0; i < 16; ++i) { float d = Xt[r][sg*16+i] - mm; s += d * d; }
    s += __shfl_xor(s, 1); s += __shfl_xor(s, 2); s += __shfl_xor(s, 4);
    if (sg == 0) rs[r] = rsqrtf(s * (1.0f / HH) + 1e-8f);
  }
  __syncthreads();
  float gg = lng[n], bb = lnb[n];
  #pragma unroll
  for (int r = 0; r < 4; ++r) Xt[r][n] = (Xt[r][n] - mu[r]) * rs[r] * gg + bb;
  __syncthreads();
  float acc[4] = {0.f, 0.f, 0.f, 0.f};
  const float* wr = fus_W1 + (size_t)n * 256;
  for (int d = 0; d < HH; d += 4) {
    float4 w = *(const float4*)(wr + d);
    #pragma unroll
    for (int r = 0; r < 4; ++r) {
      float4 a = *(const float4*)(&Xt[r][d]);
      acc[r] = fmaf(a.x, w.x, fmaf(a.y, w.y, fmaf(a.z, w.z, fmaf(a.w, w.w, acc[r]))));
    }
  }
  float hp = HP1[bidx * HH + n];
  #pragma unroll
  for (int r = 0; r < 4; ++r) {
    float v = acc[r] + hp;
    Ht[r][n] = 0.5f * v * (1.0f + erff(v * 0.70710678118654752f));
  }
  __syncthreads();
  float acc2[4] = {0.f, 0.f, 0.f, 0.f};
  wr = fus_W2 + (size_t)n * HH;
  for (int d = 0; d < HH; d += 4) {
    float4 w = *(const float4*)(wr + d);
    #pragma unroll
    for (int r = 0; r < 4; ++r) {
      float4 a = *(const float4*)(&Ht[r][d]);
      acc2[r] = fmaf(a.x, w.x, fmaf(a.y, w.y, fmaf(a.z, w.z, fmaf(a.w, w.w, acc2[r]))));
    }
  }
  float b2n = fus_b2[n];
  #pragma unroll
  for (int r = 0; r < 4; ++r) Ft[r][n] = acc2[r] + b2n;
  __syncthreads();
  if (n < 64) {
    int task = n >> 3;     // 0..7: r = task&3, which = task>>2
    int sg = n & 7;
    int r = task & 3;
    int w = task >> 2;
    int mrow = m0 + r;
    int idx = (w == 0) ? pos[mrow] : neg[mrow];
    const float* ie = item_emb + (size_t)idx * HH;
    float s = 0.f;
    #pragma unroll
    for (int i = 0; i < 16; ++i) s += Ft[r][sg * 16 + i] * ie[sg * 16 + i];
    s += __shfl_xor(s, 1); s += __shfl_xor(s, 2); s += __shfl_xor(s, 4);
    if (sg == 0) out[w * 2048 + mrow] = s;
  }
}

extern "C" void kernel_launch(void* const* d_in, const int* in_sizes, int n_in,
                              void* d_out, int out_size, void* d_ws, size_t ws_size,
                              hipStream_t stream) {
  const int*   log_seqs   = (const int*)d_in[0];
  const int*   tmat       = (const int*)d_in[1];
  const float* time_seq   = (const float*)d_in[2];
  const int*   pos_seqs   = (const int*)d_in[3];
  const int*   neg_seqs   = (const int*)d_in[4];
  const float* target_t   = (const float*)d_in[5];
  const float* item_emb   = (const float*)d_in[6];
  const float* abs_pos_K  = (const float*)d_in[7];
  const float* abs_pos_V  = (const float*)d_in[8];
  const float* time_K_emb = (const float*)d_in[9];
  const float* time_V_emb = (const float*)d_in[10];
  const float* Wq = (const float*)d_in[11];
  const float* bq = (const float*)d_in[12];
  const float* Wk = (const float*)d_in[13];
  const float* bk = (const float*)d_in[14];
  const float* Wv = (const float*)d_in[15];
  const float* bv = (const float*)d_in[16];
  const float* attn_ln_g = (const float*)d_in[17];
  const float* attn_ln_b = (const float*)d_in[18];
  const float* fwd_ln_g = (const float*)d_in[19];
  const float* fwd_ln_b = (const float*)d_in[20];
  const float* w1 = (const float*)d_in[21];
  const float* b1 = (const float*)d_in[22];
  const float* w2 = (const float*)d_in[23];
  const float* b2 = (const float*)d_in[24];
  const float* last_ln_g = (const float*)d_in[25];
  const float* last_ln_b = (const float*)d_in[26];
  const float* time_proj = (const float*)d_in[27];
  const float* lambdas = (const float*)d_in[28];
  const float* pred_W = (const float*)d_in[29];
  const float* fus_W1 = (const float*)d_in[30];
  const float* fus_b1 = (const float*)d_in[31];
  const float* fus_W2 = (const float*)d_in[32];
  const float* fus_b2 = (const float*)d_in[33];
  (void)in_sizes; (void)n_in; (void)out_size; (void)ws_size;

  float* out = (float*)d_out;
  float* ws = (float*)d_ws;
  const int M = 8 * TT;  // 2048
  float* SC6  = ws;                 // M*6
  float* SEQS = SC6 + M * 6;
  float* QN   = SEQS + M * HH;
  float* QB   = QN + M * HH;
  float* KB   = QB + M * HH;
  float* VB   = KB + M * HH;
  float* HP1  = VB + M * HH;        // 8*128

  embed_kernel<<<M, HH, 0, stream>>>(log_seqs, time_seq, item_emb, time_proj, SEQS, SC6);
  for (int l = 0; l < 2; ++l) {
    const size_t wo = (size_t)l * HH * HH;
    const size_t bo = (size_t)l * HH;
    qkv_fused<<<768, 128, 0, stream>>>(SEQS, Wq + wo, bq + bo, Wk + wo, bk + bo,
                                       Wv + wo, bv + bo, attn_ln_g + bo, attn_ln_b + bo,
                                       abs_pos_K, abs_pos_V, QN, QB, KB, VB);
    attn_fused<<<1024, 256, 0, stream>>>(QB, KB, VB, QN, log_seqs, tmat, SC6,
                                         time_K_emb, time_V_emb, lambdas, SEQS);
    ffn_fused<<<512, 128, 0, stream>>>(SEQS, w1 + wo, b1 + bo, w2 + wo, b2 + bo,
                                       fwd_ln_g + bo, fwd_ln_b + bo, log_seqs, SEQS);
  }
  hper_kernel<<<8, 128, 0, stream>>>(target_t, time_proj, pred_W, fus_W1, fus_b1, HP1);
  final_fused<<<512, 128, 0, stream>>>(SEQS, last_ln_g, last_ln_b, fus_W1, HP1,
                                       fus_W2, fus_b2, item_emb, pos_seqs, neg_seqs, out);
}